// Round 1
// baseline (287.623 us; speedup 1.0000x reference)
//
#include <hip/hip_runtime.h>

typedef __attribute__((ext_vector_type(8))) short bf16x8;
typedef __attribute__((ext_vector_type(4))) float f32x4;

__device__ __forceinline__ unsigned short f2bf(float f) {
  union { float f; unsigned u; } v; v.f = f;
  unsigned r = v.u + 0x7fffu + ((v.u >> 16) & 1u);
  return (unsigned short)(r >> 16);
}

// ---- x: f32 -> bf16, vectorized ----
__global__ void cvt_x_kernel(const float* __restrict__ in, unsigned short* __restrict__ out, int n4) {
  int i = blockIdx.x * blockDim.x + threadIdx.x;
  if (i >= n4) return;
  float4 v = ((const float4*)in)[i];
  ushort4 o; o.x = f2bf(v.x); o.y = f2bf(v.y); o.z = f2bf(v.z); o.w = f2bf(v.w);
  ((ushort4*)out)[i] = o;
}

// ---- per-expert transpose+convert: in [R][C] f32 -> out [C][R] bf16 ----
__global__ void transpose_cvt_kernel(const float* __restrict__ in, unsigned short* __restrict__ out,
                                     int R, int C) {
  __shared__ float t[32][33];
  size_t eo = (size_t)blockIdx.z * R * C;
  const float* src = in + eo;
  unsigned short* dst = out + eo;
  int c0 = blockIdx.x * 32, r0 = blockIdx.y * 32;
  int tx = threadIdx.x, ty = threadIdx.y;  // block (32,8)
#pragma unroll
  for (int i = 0; i < 32; i += 8)
    t[ty + i][tx] = src[(size_t)(r0 + ty + i) * C + (c0 + tx)];
  __syncthreads();
#pragma unroll
  for (int i = 0; i < 32; i += 8)
    dst[(size_t)(c0 + ty + i) * R + (r0 + tx)] = f2bf(t[tx][ty + i]);
}

// ---- TN GEMM: C[row, col] = sum_k Xtile[row,k] * Wtile[col,k], both K-contiguous ----
// 128x128 tile, BK=64, 4 waves (2x2 of 64x64), mfma_f32_16x16x32_bf16.
// LDS tiles [128 rows][64 k] bf16 with XOR swizzle: phys = log ^ ((row&7)<<4).
// Staged via global_load_lds width=16 with inverse-swizzled global source (rule 21).

__device__ __forceinline__ void stage_tile(const unsigned short* __restrict__ src,
                                           size_t row_stride, int row0, int k0,
                                           unsigned short* lds) {
  int t = threadIdx.x;
  int lane = t & 63;
  int w = t >> 6;
#pragma unroll
  for (int i = 0; i < 4; ++i) {
    int chunk = w * 4 + i;                 // 16 chunks of 1KB = 16KB tile
    int row = chunk * 8 + (lane >> 3);     // 128B per row -> 8 rows per chunk
    int glog = (lane & 7) ^ (row & 7);     // inverse-swizzled source granule
    const unsigned short* g = src + (size_t)(row0 + row) * row_stride + (size_t)(k0 + glog * 8);
    __builtin_amdgcn_global_load_lds((const __attribute__((address_space(1))) unsigned int*)g,
                                     (__attribute__((address_space(3))) unsigned int*)(lds + chunk * 512),
                                     16, 0, 0);
  }
}

__device__ __forceinline__ bf16x8 read_frag(const unsigned short* lds, int row, int gb) {
  int phys = (row * 128 + gb) ^ ((row & 7) << 4);
  return *(const bf16x8*)((const char*)lds + phys);
}

// MODE 0: pre[b][z][m] (bf16) = x_bf[4096x1024] . A_t[z][512 m][1024 i]^T   (K=1024)
// MODE 1: inner[b][z][h] (f32, masked) = pre[.,z,.][4096x512] . B_t[z][1024 h][512 m]^T (K=512)
template <int MODE>
__global__ __launch_bounds__(256)
void moe_gemm_kernel(const unsigned short* __restrict__ X,
                     const unsigned short* __restrict__ W,
                     unsigned short* __restrict__ pre_out,
                     float* __restrict__ inner_out,
                     const int* __restrict__ mask) {
  __shared__ unsigned short Xs[128 * 64];
  __shared__ unsigned short Ws[128 * 64];
  __shared__ float maskS[128];

  const int z = blockIdx.z;
  const int tb = blockIdx.y * 128;
  const int tn = blockIdx.x * 128;
  const int t = threadIdx.x;
  const int lane = t & 63;
  const int wv = t >> 6;
  const int wr = (wv >> 1) * 64;
  const int wc = (wv & 1) * 64;
  const int fr = lane & 15;
  const int fg = lane >> 4;  // 0..3

  const unsigned short* Xbase;
  const unsigned short* Wbase;
  size_t xstride, wstride;
  int nkt;
  if (MODE == 0) {
    Xbase = X;                         xstride = 1024;
    Wbase = W + (size_t)z * 512 * 1024; wstride = 1024;
    nkt = 16;
  } else {
    Xbase = X + (size_t)z * 512;       xstride = 16 * 512;
    Wbase = W + (size_t)z * 1024 * 512; wstride = 512;
    nkt = 8;
  }

  if (MODE == 1 && t < 128)
    maskS[t] = (mask[(size_t)(tb + t) * 16 + z] != 0) ? 1.0f : 0.0f;

  f32x4 acc[4][4] = {};

  for (int kt = 0; kt < nkt; ++kt) {
    if (kt) __syncthreads();
    stage_tile(Xbase, xstride, tb, kt * 64, Xs);
    stage_tile(Wbase, wstride, tn, kt * 64, Ws);
    __syncthreads();
#pragma unroll
    for (int kk = 0; kk < 2; ++kk) {
      const int gb = kk * 64 + fg * 16;
      bf16x8 xf[4], wf[4];
#pragma unroll
      for (int i = 0; i < 4; ++i) {
        xf[i] = read_frag(Xs, wr + i * 16 + fr, gb);
        wf[i] = read_frag(Ws, wc + i * 16 + fr, gb);
      }
#pragma unroll
      for (int mi = 0; mi < 4; ++mi)
#pragma unroll
        for (int ni = 0; ni < 4; ++ni)
          acc[mi][ni] = __builtin_amdgcn_mfma_f32_16x16x32_bf16(xf[mi], wf[ni], acc[mi][ni], 0, 0, 0);
    }
  }

  // C/D layout (m89-verified): col = lane&15, row = (lane>>4)*4 + j
  if (MODE == 0) {
#pragma unroll
    for (int mi = 0; mi < 4; ++mi) {
#pragma unroll
      for (int j = 0; j < 4; ++j) {
        int b = tb + wr + mi * 16 + fg * 4 + j;
        size_t rowbase = (size_t)b * (16 * 512) + (size_t)z * 512;
#pragma unroll
        for (int ni = 0; ni < 4; ++ni) {
          int m = tn + wc + ni * 16 + fr;
          pre_out[rowbase + m] = f2bf(acc[mi][ni][j]);
        }
      }
    }
  } else {
#pragma unroll
    for (int mi = 0; mi < 4; ++mi) {
#pragma unroll
      for (int j = 0; j < 4; ++j) {
        int bl = wr + mi * 16 + fg * 4 + j;
        float km = maskS[bl];
        size_t rowbase = (size_t)(tb + bl) * (16 * 1024) + (size_t)z * 1024;
#pragma unroll
        for (int ni = 0; ni < 4; ++ni) {
          int h = tn + wc + ni * 16 + fr;
          inner_out[rowbase + h] = acc[mi][ni][j] * km;
        }
      }
    }
  }
}

// ---- out[b][h] = sum_k inner[b][k][h] + bias[h] ----
__global__ void reduce_kernel(const float* __restrict__ inner, const float* __restrict__ bias,
                              float* __restrict__ out) {
  int i = blockIdx.x * blockDim.x + threadIdx.x;  // 4096*256 float4 slots
  int b = i >> 8;
  int h4 = i & 255;
  const float4* p = (const float4*)(inner + (size_t)b * (16 * 1024)) + h4;
  float4 s = ((const float4*)bias)[h4];
#pragma unroll
  for (int k = 0; k < 16; ++k) {
    float4 v = p[(size_t)k * 256];
    s.x += v.x; s.y += v.y; s.z += v.z; s.w += v.w;
  }
  ((float4*)out)[i] = s;
}

extern "C" void kernel_launch(void* const* d_in, const int* in_sizes, int n_in,
                              void* d_out, int out_size, void* d_ws, size_t ws_size,
                              hipStream_t stream) {
  const float* x    = (const float*)d_in[0];
  const int*   mask = (const int*)d_in[1];   // topk_mask (assumed int32)
  const float* A    = (const float*)d_in[2];
  const float* B    = (const float*)d_in[3];
  const float* bias = (const float*)d_in[4];

  float* out   = (float*)d_out;
  float* inner = (float*)d_out + (size_t)4096 * 1024;

  // workspace layout (bytes): x_bf 8MB | A_t 16MB | B_t 16MB | pre 64MB
  if (ws_size < (size_t)104 * 1024 * 1024) return;  // needs 104MB scratch
  char* ws = (char*)d_ws;
  unsigned short* x_bf = (unsigned short*)ws;
  unsigned short* A_t  = (unsigned short*)(ws + ((size_t)8 << 20));
  unsigned short* B_t  = (unsigned short*)(ws + ((size_t)24 << 20));
  unsigned short* pre  = (unsigned short*)(ws + ((size_t)40 << 20));

  cvt_x_kernel<<<4096, 256, 0, stream>>>(x, x_bf, 1048576);
  // A [16][1024 i][512 m] -> A_t [16][512 m][1024 i]
  transpose_cvt_kernel<<<dim3(16, 32, 16), dim3(32, 8), 0, stream>>>(A, A_t, 1024, 512);
  // B [16][512 m][1024 h] -> B_t [16][1024 h][512 m]
  transpose_cvt_kernel<<<dim3(32, 16, 16), dim3(32, 8), 0, stream>>>(B, B_t, 512, 1024);

  moe_gemm_kernel<0><<<dim3(4, 32, 16), 256, 0, stream>>>(x_bf, A_t, pre, nullptr, nullptr);
  moe_gemm_kernel<1><<<dim3(8, 32, 16), 256, 0, stream>>>(pre, B_t, nullptr, inner, mask);

  reduce_kernel<<<4096, 256, 0, stream>>>(inner, bias, out);
}

// Round 2
// 216.180 us; speedup vs baseline: 1.3305x; 1.3305x over previous
//
#include <hip/hip_runtime.h>

typedef __attribute__((ext_vector_type(8))) short bf16x8;
typedef __attribute__((ext_vector_type(4))) float f32x4;

__device__ __forceinline__ unsigned short f2bf(float f) {
  union { float f; unsigned u; } v; v.f = f;
  unsigned r = v.u + 0x7fffu + ((v.u >> 16) & 1u);
  return (unsigned short)(r >> 16);
}

// ---- x: f32 -> bf16, vectorized ----
__global__ void cvt_x_kernel(const float* __restrict__ in, unsigned short* __restrict__ out, int n4) {
  int i = blockIdx.x * blockDim.x + threadIdx.x;
  if (i >= n4) return;
  float4 v = ((const float4*)in)[i];
  ushort4 o; o.x = f2bf(v.x); o.y = f2bf(v.y); o.z = f2bf(v.z); o.w = f2bf(v.w);
  ((ushort4*)out)[i] = o;
}

// ---- per-expert transpose+convert: in [R][C] f32 -> out [C][R] bf16 ----
__global__ void transpose_cvt_kernel(const float* __restrict__ in, unsigned short* __restrict__ out,
                                     int R, int C) {
  __shared__ float t[32][33];
  size_t eo = (size_t)blockIdx.z * R * C;
  const float* src = in + eo;
  unsigned short* dst = out + eo;
  int c0 = blockIdx.x * 32, r0 = blockIdx.y * 32;
  int tx = threadIdx.x, ty = threadIdx.y;  // block (32,8)
#pragma unroll
  for (int i = 0; i < 32; i += 8)
    t[ty + i][tx] = src[(size_t)(r0 + ty + i) * C + (c0 + tx)];
  __syncthreads();
#pragma unroll
  for (int i = 0; i < 32; i += 8)
    dst[(size_t)(c0 + ty + i) * R + (r0 + tx)] = f2bf(t[tx][ty + i]);
}

// ---- per-expert row compaction: rows[z][0..cnt) = unmasked b indices, tail zeroed ----
__global__ void compact_kernel(const int* __restrict__ mask, int* __restrict__ rows,
                               int* __restrict__ counts) {
  int z = blockIdx.x;
  __shared__ int cnt;
  if (threadIdx.x == 0) cnt = 0;
  __syncthreads();
  int* rz = rows + (size_t)z * 4096;
  for (int i = threadIdx.x; i < 4096; i += blockDim.x) {
    bool m = mask[(size_t)i * 16 + z] != 0;
    unsigned long long bal = __ballot(m);
    int lane = threadIdx.x & 63;
    int pfx = __popcll(bal & ((1ull << lane) - 1ull));
    int tot = __popcll(bal);
    int base;
    if (lane == 0) base = atomicAdd(&cnt, tot);
    base = __shfl(base, 0);
    if (m) rz[base + pfx] = i;
  }
  __syncthreads();
  int c = cnt;
  for (int i = c + threadIdx.x; i < 4096; i += blockDim.x) rz[i] = 0;  // pad tail
  if (threadIdx.x == 0) counts[z] = c;
}

// ---- LDS staging, 128x64 bf16 tile, XOR swizzle phys = log ^ ((row&7)<<4) ----
__device__ __forceinline__ void stage_tile(const unsigned short* __restrict__ src,
                                           size_t row_stride, int row0, int k0,
                                           unsigned short* lds) {
  int t = threadIdx.x;
  int lane = t & 63;
  int w = t >> 6;
#pragma unroll
  for (int i = 0; i < 4; ++i) {
    int chunk = w * 4 + i;
    int row = chunk * 8 + (lane >> 3);
    int glog = (lane & 7) ^ (row & 7);
    const unsigned short* g = src + (size_t)(row0 + row) * row_stride + (size_t)(k0 + glog * 8);
    __builtin_amdgcn_global_load_lds((const __attribute__((address_space(1))) unsigned int*)g,
                                     (__attribute__((address_space(3))) unsigned int*)(lds + chunk * 512),
                                     16, 0, 0);
  }
}

// gather variant: per-lane row index from LDS list (global source is per-lane — legal)
__device__ __forceinline__ void stage_tile_gather(const unsigned short* __restrict__ src,
                                                  const int* __restrict__ rowsS, int k0,
                                                  unsigned short* lds) {
  int t = threadIdx.x;
  int lane = t & 63;
  int w = t >> 6;
#pragma unroll
  for (int i = 0; i < 4; ++i) {
    int chunk = w * 4 + i;
    int row = chunk * 8 + (lane >> 3);
    int glog = (lane & 7) ^ (row & 7);
    const unsigned short* g = src + (size_t)rowsS[row] * 1024 + (size_t)(k0 + glog * 8);
    __builtin_amdgcn_global_load_lds((const __attribute__((address_space(1))) unsigned int*)g,
                                     (__attribute__((address_space(3))) unsigned int*)(lds + chunk * 512),
                                     16, 0, 0);
  }
}

__device__ __forceinline__ bf16x8 read_frag(const unsigned short* lds, int row, int gb) {
  int phys = (row * 128 + gb) ^ ((row & 7) << 4);
  return *(const bf16x8*)((const char*)lds + phys);
}

// MODE 0: pre[z][r][m] (bf16) = x_bf[rows[z][r]] . A_t[z][512 m][1024 i]^T   (K=1024)
// MODE 1: inner[rows[z][r]][z][h] (f32) = pre[z][r] . B_t[z][1024 h][512 m]^T (K=512)
template <int MODE>
__global__ __launch_bounds__(256)
void moe_gemm_kernel(const unsigned short* __restrict__ X,
                     const unsigned short* __restrict__ W,
                     unsigned short* __restrict__ pre_out,
                     float* __restrict__ inner_out,
                     const int* __restrict__ rows,
                     const int* __restrict__ counts) {
  const int z = blockIdx.z;
  const int cnt = counts[z];
  const int tb = blockIdx.y * 128;
  if (tb >= cnt) return;  // uniform early exit over compacted rows

  __shared__ unsigned short Xs[128 * 64];
  __shared__ unsigned short Ws[128 * 64];
  __shared__ int rowsS[128];

  const int tn = blockIdx.x * 128;
  const int t = threadIdx.x;
  const int lane = t & 63;
  const int wv = t >> 6;
  const int wr = (wv >> 1) * 64;
  const int wc = (wv & 1) * 64;
  const int fr = lane & 15;
  const int fg = lane >> 4;

  if (t < 128) rowsS[t] = rows[(size_t)z * 4096 + tb + t];

  const unsigned short* Wbase;
  const unsigned short* Xbase;
  size_t wstride, xstride;
  int nkt;
  if (MODE == 0) {
    Xbase = X;                            xstride = 1024;   // gathered
    Wbase = W + (size_t)z * 512 * 1024;   wstride = 1024;
    nkt = 16;
  } else {
    Xbase = X + (size_t)z * 4096 * 512;   xstride = 512;    // compact-contiguous
    Wbase = W + (size_t)z * 1024 * 512;   wstride = 512;
    nkt = 8;
  }

  __syncthreads();  // rowsS ready before gather staging

  f32x4 acc[4][4] = {};

  for (int kt = 0; kt < nkt; ++kt) {
    if (kt) __syncthreads();
    if (MODE == 0)
      stage_tile_gather(Xbase, rowsS, kt * 64, Xs);
    else
      stage_tile(Xbase, xstride, tb, kt * 64, Xs);
    stage_tile(Wbase, wstride, tn, kt * 64, Ws);
    __syncthreads();
#pragma unroll
    for (int kk = 0; kk < 2; ++kk) {
      const int gb = kk * 64 + fg * 16;
      bf16x8 xf[4], wf[4];
#pragma unroll
      for (int i = 0; i < 4; ++i) {
        xf[i] = read_frag(Xs, wr + i * 16 + fr, gb);
        wf[i] = read_frag(Ws, wc + i * 16 + fr, gb);
      }
#pragma unroll
      for (int mi = 0; mi < 4; ++mi)
#pragma unroll
        for (int ni = 0; ni < 4; ++ni)
          acc[mi][ni] = __builtin_amdgcn_mfma_f32_16x16x32_bf16(xf[mi], wf[ni], acc[mi][ni], 0, 0, 0);
    }
  }

  // C/D layout: col = lane&15, row = (lane>>4)*4 + j
  if (MODE == 0) {
#pragma unroll
    for (int mi = 0; mi < 4; ++mi) {
#pragma unroll
      for (int j = 0; j < 4; ++j) {
        int rl = wr + mi * 16 + fg * 4 + j;
        size_t rowbase = (size_t)z * 4096 * 512 + (size_t)(tb + rl) * 512;
#pragma unroll
        for (int ni = 0; ni < 4; ++ni) {
          int m = tn + wc + ni * 16 + fr;
          pre_out[rowbase + m] = f2bf(acc[mi][ni][j]);  // padded rows write garbage-but-finite; never scattered
        }
      }
    }
  } else {
#pragma unroll
    for (int mi = 0; mi < 4; ++mi) {
#pragma unroll
      for (int j = 0; j < 4; ++j) {
        int rl = wr + mi * 16 + fg * 4 + j;
        if (tb + rl < cnt) {
          int b = rowsS[rl];
          size_t rowbase = (size_t)b * (16 * 1024) + (size_t)z * 1024;
#pragma unroll
          for (int ni = 0; ni < 4; ++ni) {
            int h = tn + wc + ni * 16 + fr;
            inner_out[rowbase + h] = acc[mi][ni][j];
          }
        }
      }
    }
  }
}

// ---- out[b] = bias + sum_{k unmasked} inner[b][k]; zero-fill masked inner rows ----
__global__ void reduce_zero_kernel(float* __restrict__ inner, const float* __restrict__ bias,
                                   const int* __restrict__ mask, float* __restrict__ out) {
  int b = blockIdx.x;
  int t = threadIdx.x;  // 256
  __shared__ int mrow[16];
  if (t < 16) mrow[t] = mask[(size_t)b * 16 + t];
  __syncthreads();
  float4 s = ((const float4*)bias)[t];
  float4* ip = (float4*)(inner + (size_t)b * (16 * 1024)) + t;
  const float4 z4 = {0.f, 0.f, 0.f, 0.f};
#pragma unroll
  for (int k = 0; k < 16; ++k) {
    if (mrow[k]) {
      float4 v = ip[(size_t)k * 256];
      s.x += v.x; s.y += v.y; s.z += v.z; s.w += v.w;
    } else {
      ip[(size_t)k * 256] = z4;
    }
  }
  ((float4*)out)[(size_t)b * 256 + t] = s;
}

extern "C" void kernel_launch(void* const* d_in, const int* in_sizes, int n_in,
                              void* d_out, int out_size, void* d_ws, size_t ws_size,
                              hipStream_t stream) {
  const float* x    = (const float*)d_in[0];
  const int*   mask = (const int*)d_in[1];
  const float* A    = (const float*)d_in[2];
  const float* B    = (const float*)d_in[3];
  const float* bias = (const float*)d_in[4];

  float* out   = (float*)d_out;
  float* inner = (float*)d_out + (size_t)4096 * 1024;

  // ws layout: x_bf 8MiB | A_t 16MiB | B_t 16MiB | pre 64MiB | rows 256KiB | counts
  if (ws_size < 109314112ull) return;  // 104MiB + rows/counts
  char* ws = (char*)d_ws;
  unsigned short* x_bf = (unsigned short*)ws;
  unsigned short* A_t  = (unsigned short*)(ws + ((size_t)8 << 20));
  unsigned short* B_t  = (unsigned short*)(ws + ((size_t)24 << 20));
  unsigned short* pre  = (unsigned short*)(ws + ((size_t)40 << 20));
  int* rows            = (int*)(ws + ((size_t)104 << 20));
  int* counts          = (int*)(ws + ((size_t)104 << 20) + 262144);

  cvt_x_kernel<<<4096, 256, 0, stream>>>(x, x_bf, 1048576);
  transpose_cvt_kernel<<<dim3(16, 32, 16), dim3(32, 8), 0, stream>>>(A, A_t, 1024, 512);
  transpose_cvt_kernel<<<dim3(32, 16, 16), dim3(32, 8), 0, stream>>>(B, B_t, 512, 1024);
  compact_kernel<<<16, 256, 0, stream>>>(mask, rows, counts);

  moe_gemm_kernel<0><<<dim3(4, 32, 16), 256, 0, stream>>>(x_bf, A_t, pre, nullptr, rows, counts);
  moe_gemm_kernel<1><<<dim3(8, 32, 16), 256, 0, stream>>>(pre, B_t, nullptr, inner, rows, counts);

  reduce_zero_kernel<<<4096, 256, 0, stream>>>(inner, bias, mask, out);
}